// Round 1
// 162.168 us; speedup vs baseline: 1.0238x; 1.0238x over previous
//
#include <hip/hip_runtime.h>

#define IMG 512
#define NPLANES 48            // 16*3
#define TW 64                 // output tile width
#define TH 32                 // output tile height
#define RD 5
#define KW 11
#define VC (TW + 2*RD)        // 74 columns of vertical sums
#define WPAD 80               // padded LDS row (16B-aligned float4 rows)
#define NTX (IMG/TW)          // 8
#define NTY (IMG/TH)          // 16
#define TPP (NTX*NTY)         // 128
#define NBLOCKS (NPLANES*TPP) // 6144
#define NPIX (16.0f*3.0f*512.0f*512.0f)

__device__ __forceinline__ float fast_rcp(float d) {
    float r = __builtin_amdgcn_rcpf(d);
    r = r * (2.0f - d * r);   // one Newton step: ~1e-7 rel error
    return r;
}

__global__ __launch_bounds__(256) void ssim_kernel(
    const float* __restrict__ img1, const float* __restrict__ img2,
    float* __restrict__ partial)
{
    // vertical windowed sums: mu1, mu2, E[aa], E[bb], E[ab]
    __shared__ float v[5][TH][WPAD];
    __shared__ float wsum[4];

    const float cw[KW] = {
        0.00102838f, 0.00759876f, 0.03600077f, 0.10936069f, 0.21300553f,
        0.26601172f,
        0.21300553f, 0.10936069f, 0.03600077f, 0.00759876f, 0.00102838f
    };

    const int tid = threadIdx.x;
    const int blk = blockIdx.x;
    const int plane = blk / TPP;
    const int t     = blk % TPP;
    const int ty0 = (t / NTX) * TH;
    const int tx0 = (t % NTX) * TW;
    const float* __restrict__ p1 = img1 + (size_t)plane * IMG * IMG;
    const float* __restrict__ p2 = img2 + (size_t)plane * IMG * IMG;

    // block-uniform: no element touches the image border -> skip all predication
    const bool interior = (tx0 >= RD) && (tx0 + TW + RD <= IMG) &&
                          (ty0 >= RD) && (ty0 + TH + RD <= IMG);

    // ---- pass 1: vertical 11-tap on raw + product images, global -> LDS ----
    // 296 tasks: (col 0..73) x (4 row-segments of 8 outputs)
    for (int task = tid; task < VC * 4; task += 256) {
        const int col = task % VC;       // storage column
        const int seg = task / VC;       // 0..3
        const int gx  = tx0 + col - RD;
        const int r0  = seg * 8;

        float a[18], b[18];
        if (interior) {
            // uniform base + 32-bit offset -> saddr-form loads, 1 add per row
            const unsigned off0 = (unsigned)((ty0 + r0 - RD) * IMG + gx);
            #pragma unroll
            for (int k = 0; k < 18; k++) {
                a[k] = p1[off0 + (unsigned)(k * IMG)];
                b[k] = p2[off0 + (unsigned)(k * IMG)];
            }
        } else {
            const bool xok = (gx >= 0) && (gx < IMG);
            #pragma unroll
            for (int k = 0; k < 18; k++) {
                const int gy = ty0 + r0 + k - RD;
                const bool ok = xok && (gy >= 0) && (gy < IMG);
                const int gi = gy * IMG + gx;
                a[k] = ok ? p1[gi] : 0.f;
                b[k] = ok ? p2[gi] : 0.f;
            }
        }

        // accumulate-style vertical conv: products computed ONCE per input row
        // (5 FMA/tap + 3 mul/row vs previous 7 ops/tap)
        float s0[8], s1[8], s2[8], s3[8], s4[8];
        #pragma unroll
        for (int o = 0; o < 8; o++) {
            s0[o] = 0.f; s1[o] = 0.f; s2[o] = 0.f; s3[o] = 0.f; s4[o] = 0.f;
        }

        #pragma unroll
        for (int k = 0; k < 18; k++) {
            const float av = a[k], bv = b[k];
            const float aa = av * av;
            const float bb = bv * bv;
            const float ab = av * bv;
            #pragma unroll
            for (int o = 0; o < 8; o++) {
                const int d = k - o;            // tap index, compile-time
                if (d >= 0 && d < KW) {
                    const float w = cw[d];
                    s0[o] += w * av;
                    s1[o] += w * bv;
                    s2[o] += w * aa;
                    s3[o] += w * bb;
                    s4[o] += w * ab;
                }
            }
        }

        #pragma unroll
        for (int o = 0; o < 8; o++) {
            const int r = r0 + o;
            v[0][r][col] = s0[o];
            v[1][r][col] = s1[o];
            v[2][r][col] = s2[o];
            v[3][r][col] = s3[o];
            v[4][r][col] = s4[o];
        }
    }
    __syncthreads();

    // ---- pass 2: horizontal 11-tap (vectorized ds_read_b128) + SSIM ----
    const float C1 = 1e-4f;
    const float C2 = 9e-4f;
    float acc = 0.f;
    #pragma unroll
    for (int it = 0; it < 2; it++) {
        const int task = tid + it * 256;     // 0..511
        const int j = task & 15;             // float4 group: outputs 4j..4j+3
        const int r = task >> 4;             // row 0..31
        float res[5][4];
        #pragma unroll
        for (int arr = 0; arr < 5; arr++) {
            const float4* row = (const float4*)&v[arr][r][0];
            const float4 q0 = row[j + 0];
            const float4 q1 = row[j + 1];
            const float4 q2 = row[j + 2];
            const float4 q3 = row[j + 3];
            const float vals[16] = {
                q0.x, q0.y, q0.z, q0.w,
                q1.x, q1.y, q1.z, q1.w,
                q2.x, q2.y, q2.z, q2.w,
                q3.x, q3.y, q3.z, q3.w
            };
            #pragma unroll
            for (int o = 0; o < 4; o++) {
                float s = 0.f;
                #pragma unroll
                for (int d = 0; d < KW; d++)
                    s += cw[d] * vals[o + d];
                res[arr][o] = s;
            }
        }
        #pragma unroll
        for (int o = 0; o < 4; o++) {
            const float mu1 = res[0][o];
            const float mu2 = res[1][o];
            const float x11 = res[2][o];
            const float x22 = res[3][o];
            const float x12 = res[4][o];
            const float mu1s = mu1 * mu1;
            const float mu2s = mu2 * mu2;
            const float mu12 = mu1 * mu2;
            const float s1  = x11 - mu1s;
            const float s2  = x22 - mu2s;
            const float s12 = x12 - mu12;
            const float num = (2.f * mu12 + C1) * (2.f * s12 + C2);
            const float den = (mu1s + mu2s + C1) * (s1 + s2 + C2);
            acc += num * fast_rcp(den);
        }
    }

    // ---- block reduction ----
    #pragma unroll
    for (int off = 32; off > 0; off >>= 1)
        acc += __shfl_down(acc, off, 64);
    const int lane = tid & 63;
    const int wv_i = tid >> 6;
    if (lane == 0) wsum[wv_i] = acc;
    __syncthreads();
    if (tid == 0)
        partial[blk] = (wsum[0] + wsum[1]) + (wsum[2] + wsum[3]);
}

__global__ __launch_bounds__(256) void ssim_reduce_kernel(
    const float* __restrict__ partial, float* __restrict__ out)
{
    float acc = 0.f;
    for (int i = threadIdx.x; i < NBLOCKS; i += 256)
        acc += partial[i];
    #pragma unroll
    for (int off = 32; off > 0; off >>= 1)
        acc += __shfl_down(acc, off, 64);
    __shared__ float wsum[4];
    const int lane = threadIdx.x & 63;
    const int wv_i = threadIdx.x >> 6;
    if (lane == 0) wsum[wv_i] = acc;
    __syncthreads();
    if (threadIdx.x == 0)
        out[0] = ((wsum[0] + wsum[1]) + (wsum[2] + wsum[3])) * (1.0f / NPIX);
}

extern "C" void kernel_launch(void* const* d_in, const int* in_sizes, int n_in,
                              void* d_out, int out_size, void* d_ws, size_t ws_size,
                              hipStream_t stream) {
    const float* img1 = (const float*)d_in[0];
    const float* img2 = (const float*)d_in[1];
    float* out = (float*)d_out;
    float* partial = (float*)d_ws;   // NBLOCKS floats of scratch

    ssim_kernel<<<NBLOCKS, 256, 0, stream>>>(img1, img2, partial);
    ssim_reduce_kernel<<<1, 256, 0, stream>>>(partial, out);
}

// Round 3
// 156.580 us; speedup vs baseline: 1.0604x; 1.0357x over previous
//
#include <hip/hip_runtime.h>

#define IMG 512
#define NPLANES 48            // 16*3
#define TW 64                 // output tile width
#define TH 32                 // output tile height
#define RD 5
#define KW 11
#define VC (TW + 2*RD)        // 74 columns of vertical sums
#define WPAD 80               // padded LDS row for scalar (E[ab]) array
#define PRW (2*VC + 4)        // 152 floats = 608B interleaved pair rows (16B-aligned)
#define NTX (IMG/TW)          // 8
#define NTY (IMG/TH)          // 16
#define TPP (NTX*NTY)         // 128
#define NBLOCKS (NPLANES*TPP) // 6144
#define NPIX (16.0f*3.0f*512.0f*512.0f)

typedef float v2f __attribute__((ext_vector_type(2)));

// Packed fp32 math (VOP3P, full-rate on CDNA2+: 2 fp32 FMA / instr).
// The compiler never forms these from scalar code; emit directly.
__device__ __forceinline__ v2f pk_fma(v2f a, v2f b, v2f c) {
    v2f d;
    asm("v_pk_fma_f32 %0, %1, %2, %3" : "=v"(d) : "v"(a), "v"(b), "v"(c));
    return d;
}
__device__ __forceinline__ v2f pk_mul(v2f a, v2f b) {
    v2f d;
    asm("v_pk_mul_f32 %0, %1, %2" : "=v"(d) : "v"(a), "v"(b));
    return d;
}

__device__ __forceinline__ float fast_rcp(float d) {
    float r = __builtin_amdgcn_rcpf(d);
    r = r * (2.0f - d * r);   // one Newton step: ~1e-7 rel error
    return r;
}

__global__ __launch_bounds__(256) void ssim_kernel(
    const float* __restrict__ img1, const float* __restrict__ img2,
    float* __restrict__ partial)
{
    // channel-interleaved vertical sums:
    //   v01[r][2c..2c+1] = (mu1, mu2) vertical sums at column c
    //   v23[r][2c..2c+1] = (E[aa], E[bb])
    //   vZ [r][c]        = E[ab]
    __shared__ __align__(16) float v01[TH][PRW];
    __shared__ __align__(16) float v23[TH][PRW];
    __shared__ __align__(16) float vZ [TH][WPAD];
    __shared__ float wsum[4];

    const float cw[KW] = {
        0.00102838f, 0.00759876f, 0.03600077f, 0.10936069f, 0.21300553f,
        0.26601172f,
        0.21300553f, 0.10936069f, 0.03600077f, 0.00759876f, 0.00102838f
    };
    const v2f cw2[KW] = {
        {0.00102838f,0.00102838f}, {0.00759876f,0.00759876f},
        {0.03600077f,0.03600077f}, {0.10936069f,0.10936069f},
        {0.21300553f,0.21300553f}, {0.26601172f,0.26601172f},
        {0.21300553f,0.21300553f}, {0.10936069f,0.10936069f},
        {0.03600077f,0.03600077f}, {0.00759876f,0.00759876f},
        {0.00102838f,0.00102838f}
    };

    const int tid = threadIdx.x;
    const int blk = blockIdx.x;
    const int plane = blk / TPP;
    const int t     = blk % TPP;
    const int ty0 = (t / NTX) * TH;
    const int tx0 = (t % NTX) * TW;
    const float* __restrict__ p1 = img1 + (size_t)plane * IMG * IMG;
    const float* __restrict__ p2 = img2 + (size_t)plane * IMG * IMG;

    // block-uniform: no element touches the image border -> skip all predication
    const bool interior = (tx0 >= RD) && (tx0 + TW + RD <= IMG) &&
                          (ty0 >= RD) && (ty0 + TH + RD <= IMG);

    // ---- pass 1: vertical 11-tap on raw + product images, global -> LDS ----
    // 296 tasks: (col 0..73) x (4 row-segments of 8 outputs)
    for (int task = tid; task < VC * 4; task += 256) {
        const int col = task % VC;       // storage column
        const int seg = task / VC;       // 0..3
        const int gx  = tx0 + col - RD;
        const int r0  = seg * 8;

        float a[18], b[18];
        if (interior) {
            // uniform base + 32-bit offset -> saddr-form loads
            const unsigned off0 = (unsigned)((ty0 + r0 - RD) * IMG + gx);
            #pragma unroll
            for (int k = 0; k < 18; k++) {
                a[k] = p1[off0 + (unsigned)(k * IMG)];
                b[k] = p2[off0 + (unsigned)(k * IMG)];
            }
        } else {
            const bool xok = (gx >= 0) && (gx < IMG);
            #pragma unroll
            for (int k = 0; k < 18; k++) {
                const int gy = ty0 + r0 + k - RD;
                const bool ok = xok && (gy >= 0) && (gy < IMG);
                const int gi = gy * IMG + gx;
                a[k] = ok ? p1[gi] : 0.f;
                b[k] = ok ? p2[gi] : 0.f;
            }
        }

        // packed vertical conv: per tap 2 pk_fma + 1 fma (was 5 fma)
        v2f sAB[8], sXY[8];
        float sZ[8];
        #pragma unroll
        for (int o = 0; o < 8; o++) {
            sAB[o] = (v2f){0.f, 0.f};
            sXY[o] = (v2f){0.f, 0.f};
            sZ[o]  = 0.f;
        }

        #pragma unroll
        for (int k = 0; k < 18; k++) {
            v2f rab; rab.x = a[k]; rab.y = b[k];
            const v2f rxy = pk_mul(rab, rab);        // (aa, bb)
            const float ab = a[k] * b[k];
            #pragma unroll
            for (int o = 0; o < 8; o++) {
                const int d = k - o;                 // tap index, compile-time
                if (d >= 0 && d < KW) {
                    sAB[o] = pk_fma(cw2[d], rab, sAB[o]);
                    sXY[o] = pk_fma(cw2[d], rxy, sXY[o]);
                    sZ[o]  = fmaf(cw[d], ab, sZ[o]);
                }
            }
        }

        #pragma unroll
        for (int o = 0; o < 8; o++) {
            const int r = r0 + o;
            *(v2f*)&v01[r][2*col] = sAB[o];
            *(v2f*)&v23[r][2*col] = sXY[o];
            vZ[r][col] = sZ[o];
        }
    }
    __syncthreads();

    // ---- pass 2: horizontal 11-tap (packed) + SSIM ----
    const float C1 = 1e-4f;
    const float C2 = 9e-4f;
    const v2f NEG1 = {-1.f, -1.f};
    float acc = 0.f;
    #pragma unroll
    for (int it = 0; it < 2; it++) {
        const int task = tid + it * 256;     // 0..511
        const int j = task & 15;             // group: outputs 4j..4j+3
        const int r = task >> 4;             // row 0..31

        // (mu1,mu2) pairs: need pairs 4j .. 4j+13 -> exactly 7 float4 reads
        v2f prAB[14], prXY[14];
        {
            const float4* rowp = (const float4*)&v01[r][0];
            #pragma unroll
            for (int i = 0; i < 7; i++) {
                const float4 q = rowp[2*j + i];
                prAB[2*i]   = (v2f){q.x, q.y};
                prAB[2*i+1] = (v2f){q.z, q.w};
            }
        }
        {
            const float4* rowp = (const float4*)&v23[r][0];
            #pragma unroll
            for (int i = 0; i < 7; i++) {
                const float4 q = rowp[2*j + i];
                prXY[2*i]   = (v2f){q.x, q.y};
                prXY[2*i+1] = (v2f){q.z, q.w};
            }
        }
        float zv[16];
        {
            const float4* rowp = (const float4*)&vZ[r][0];
            #pragma unroll
            for (int i = 0; i < 4; i++) {
                const float4 q = rowp[j + i];
                zv[4*i] = q.x; zv[4*i+1] = q.y; zv[4*i+2] = q.z; zv[4*i+3] = q.w;
            }
        }

        #pragma unroll
        for (int o = 0; o < 4; o++) {
            v2f M  = (v2f){0.f, 0.f};   // (mu1, mu2)
            v2f X  = (v2f){0.f, 0.f};   // (E[aa], E[bb])
            float z = 0.f;              // E[ab]
            #pragma unroll
            for (int d = 0; d < KW; d++) {
                M = pk_fma(cw2[d], prAB[o + d], M);
                X = pk_fma(cw2[d], prXY[o + d], X);
                z = fmaf(cw[d], zv[o + d], z);
            }
            const v2f M2 = pk_mul(M, M);           // (mu1^2, mu2^2)
            const v2f S  = pk_fma(M2, NEG1, X);    // (sigma1_sq, sigma2_sq)
            const float mu12 = M.x * M.y;
            const float s12  = z - mu12;
            const float num = fmaf(2.f, mu12, C1) * fmaf(2.f, s12, C2);
            const float den = (M2.x + M2.y + C1) * (S.x + S.y + C2);
            acc += num * fast_rcp(den);
        }
    }

    // ---- block reduction ----
    #pragma unroll
    for (int off = 32; off > 0; off >>= 1)
        acc += __shfl_down(acc, off, 64);
    const int lane = tid & 63;
    const int wv_i = tid >> 6;
    if (lane == 0) wsum[wv_i] = acc;
    __syncthreads();
    if (tid == 0)
        partial[blk] = (wsum[0] + wsum[1]) + (wsum[2] + wsum[3]);
}

__global__ __launch_bounds__(256) void ssim_reduce_kernel(
    const float* __restrict__ partial, float* __restrict__ out)
{
    float acc = 0.f;
    for (int i = threadIdx.x; i < NBLOCKS; i += 256)
        acc += partial[i];
    #pragma unroll
    for (int off = 32; off > 0; off >>= 1)
        acc += __shfl_down(acc, off, 64);
    __shared__ float wsum[4];
    const int lane = threadIdx.x & 63;
    const int wv_i = threadIdx.x >> 6;
    if (lane == 0) wsum[wv_i] = acc;
    __syncthreads();
    if (threadIdx.x == 0)
        out[0] = ((wsum[0] + wsum[1]) + (wsum[2] + wsum[3])) * (1.0f / NPIX);
}

extern "C" void kernel_launch(void* const* d_in, const int* in_sizes, int n_in,
                              void* d_out, int out_size, void* d_ws, size_t ws_size,
                              hipStream_t stream) {
    const float* img1 = (const float*)d_in[0];
    const float* img2 = (const float*)d_in[1];
    float* out = (float*)d_out;
    float* partial = (float*)d_ws;   // NBLOCKS floats of scratch

    ssim_kernel<<<NBLOCKS, 256, 0, stream>>>(img1, img2, partial);
    ssim_reduce_kernel<<<1, 256, 0, stream>>>(partial, out);
}

// Round 4
// 148.443 us; speedup vs baseline: 1.1185x; 1.0548x over previous
//
#include <hip/hip_runtime.h>

#define IMG 512
#define NPLANES 48            // 16*3
#define TW 64                 // output tile width
#define TH 32                 // output tile height
#define RD 5
#define KW 11
#define VC (TW + 2*RD)        // 74 columns of vertical sums
#define WPAD 80               // padded LDS row for scalar (E[ab]) array
#define PRW (2*VC + 4)        // 152 floats = 608B interleaved pair rows (16B-aligned)
#define NTX (IMG/TW)          // 8
#define NTY (IMG/TH)          // 16
#define TPP (NTX*NTY)         // 128
#define NBLOCKS (NPLANES*TPP) // 6144
#define BLK_T 512             // threads/block: 3 blocks/CU -> 24 waves/CU (was 12)
#define NPIX (16.0f*3.0f*512.0f*512.0f)

typedef float v2f __attribute__((ext_vector_type(2)));

// Packed fp32 math (VOP3P, full-rate on CDNA2+: 2 fp32 FMA / instr).
// The compiler never forms these from scalar code; emit directly.
__device__ __forceinline__ v2f pk_fma(v2f a, v2f b, v2f c) {
    v2f d;
    asm("v_pk_fma_f32 %0, %1, %2, %3" : "=v"(d) : "v"(a), "v"(b), "v"(c));
    return d;
}
__device__ __forceinline__ v2f pk_mul(v2f a, v2f b) {
    v2f d;
    asm("v_pk_mul_f32 %0, %1, %2" : "=v"(d) : "v"(a), "v"(b));
    return d;
}

__device__ __forceinline__ float fast_rcp(float d) {
    float r = __builtin_amdgcn_rcpf(d);
    r = r * (2.0f - d * r);   // one Newton step: ~1e-7 rel error
    return r;
}

__global__ __launch_bounds__(BLK_T) void ssim_kernel(
    const float* __restrict__ img1, const float* __restrict__ img2,
    float* __restrict__ partial)
{
    // channel-interleaved vertical sums:
    //   v01[r][2c..2c+1] = (mu1, mu2) vertical sums at column c
    //   v23[r][2c..2c+1] = (E[aa], E[bb])
    //   vZ [r][c]        = E[ab]
    __shared__ __align__(16) float v01[TH][PRW];
    __shared__ __align__(16) float v23[TH][PRW];
    __shared__ __align__(16) float vZ [TH][WPAD];
    __shared__ float wsum[8];

    const float cw[KW] = {
        0.00102838f, 0.00759876f, 0.03600077f, 0.10936069f, 0.21300553f,
        0.26601172f,
        0.21300553f, 0.10936069f, 0.03600077f, 0.00759876f, 0.00102838f
    };
    const v2f cw2[KW] = {
        {0.00102838f,0.00102838f}, {0.00759876f,0.00759876f},
        {0.03600077f,0.03600077f}, {0.10936069f,0.10936069f},
        {0.21300553f,0.21300553f}, {0.26601172f,0.26601172f},
        {0.21300553f,0.21300553f}, {0.10936069f,0.10936069f},
        {0.03600077f,0.03600077f}, {0.00759876f,0.00759876f},
        {0.00102838f,0.00102838f}
    };

    const int tid = threadIdx.x;
    const int blk = blockIdx.x;
    const int plane = blk / TPP;
    const int t     = blk % TPP;
    const int ty0 = (t / NTX) * TH;
    const int tx0 = (t % NTX) * TW;
    const float* __restrict__ p1 = img1 + (size_t)plane * IMG * IMG;
    const float* __restrict__ p2 = img2 + (size_t)plane * IMG * IMG;

    // block-uniform: no element touches the image border -> skip all predication
    const bool interior = (tx0 >= RD) && (tx0 + TW + RD <= IMG) &&
                          (ty0 >= RD) && (ty0 + TH + RD <= IMG);

    // ---- pass 1: vertical 11-tap on raw + product images, global -> LDS ----
    // 296 tasks: (col 0..73) x (4 row-segments of 8 outputs); single round,
    // threads >= 296 idle to the barrier (their waves free issue slots for
    // the other resident blocks on this CU).
    if (tid < VC * 4) {
        const int task = tid;
        const int col = task % VC;       // storage column
        const int seg = task / VC;       // 0..3
        const int gx  = tx0 + col - RD;
        const int r0  = seg * 8;

        float a[18], b[18];
        if (interior) {
            // uniform base + 32-bit offset -> saddr-form loads
            const unsigned off0 = (unsigned)((ty0 + r0 - RD) * IMG + gx);
            #pragma unroll
            for (int k = 0; k < 18; k++) {
                a[k] = p1[off0 + (unsigned)(k * IMG)];
                b[k] = p2[off0 + (unsigned)(k * IMG)];
            }
        } else {
            const bool xok = (gx >= 0) && (gx < IMG);
            #pragma unroll
            for (int k = 0; k < 18; k++) {
                const int gy = ty0 + r0 + k - RD;
                const bool ok = xok && (gy >= 0) && (gy < IMG);
                const int gi = gy * IMG + gx;
                a[k] = ok ? p1[gi] : 0.f;
                b[k] = ok ? p2[gi] : 0.f;
            }
        }

        // packed vertical conv: per tap 2 pk_fma + 1 fma
        v2f sAB[8], sXY[8];
        float sZ[8];
        #pragma unroll
        for (int o = 0; o < 8; o++) {
            sAB[o] = (v2f){0.f, 0.f};
            sXY[o] = (v2f){0.f, 0.f};
            sZ[o]  = 0.f;
        }

        #pragma unroll
        for (int k = 0; k < 18; k++) {
            v2f rab; rab.x = a[k]; rab.y = b[k];
            const v2f rxy = pk_mul(rab, rab);        // (aa, bb)
            const float ab = a[k] * b[k];
            #pragma unroll
            for (int o = 0; o < 8; o++) {
                const int d = k - o;                 // tap index, compile-time
                if (d >= 0 && d < KW) {
                    sAB[o] = pk_fma(cw2[d], rab, sAB[o]);
                    sXY[o] = pk_fma(cw2[d], rxy, sXY[o]);
                    sZ[o]  = fmaf(cw[d], ab, sZ[o]);
                }
            }
        }

        #pragma unroll
        for (int o = 0; o < 8; o++) {
            const int r = r0 + o;
            *(v2f*)&v01[r][2*col] = sAB[o];
            *(v2f*)&v23[r][2*col] = sXY[o];
            vZ[r][col] = sZ[o];
        }
    }
    __syncthreads();

    // ---- pass 2: horizontal 11-tap (packed) + SSIM; exactly 1 task/thread ----
    const float C1 = 1e-4f;
    const float C2 = 9e-4f;
    const v2f NEG1 = {-1.f, -1.f};
    float acc = 0.f;
    {
        const int task = tid;                // 0..511
        const int j = task & 15;             // group: outputs 4j..4j+3
        const int r = task >> 4;             // row 0..31

        // (mu1,mu2) pairs: need pairs 4j .. 4j+13 -> exactly 7 float4 reads
        v2f prAB[14], prXY[14];
        {
            const float4* rowp = (const float4*)&v01[r][0];
            #pragma unroll
            for (int i = 0; i < 7; i++) {
                const float4 q = rowp[2*j + i];
                prAB[2*i]   = (v2f){q.x, q.y};
                prAB[2*i+1] = (v2f){q.z, q.w};
            }
        }
        {
            const float4* rowp = (const float4*)&v23[r][0];
            #pragma unroll
            for (int i = 0; i < 7; i++) {
                const float4 q = rowp[2*j + i];
                prXY[2*i]   = (v2f){q.x, q.y};
                prXY[2*i+1] = (v2f){q.z, q.w};
            }
        }
        float zv[16];
        {
            const float4* rowp = (const float4*)&vZ[r][0];
            #pragma unroll
            for (int i = 0; i < 4; i++) {
                const float4 q = rowp[j + i];
                zv[4*i] = q.x; zv[4*i+1] = q.y; zv[4*i+2] = q.z; zv[4*i+3] = q.w;
            }
        }

        #pragma unroll
        for (int o = 0; o < 4; o++) {
            v2f M  = (v2f){0.f, 0.f};   // (mu1, mu2)
            v2f X  = (v2f){0.f, 0.f};   // (E[aa], E[bb])
            float z = 0.f;              // E[ab]
            #pragma unroll
            for (int d = 0; d < KW; d++) {
                M = pk_fma(cw2[d], prAB[o + d], M);
                X = pk_fma(cw2[d], prXY[o + d], X);
                z = fmaf(cw[d], zv[o + d], z);
            }
            const v2f M2 = pk_mul(M, M);           // (mu1^2, mu2^2)
            const v2f S  = pk_fma(M2, NEG1, X);    // (sigma1_sq, sigma2_sq)
            const float mu12 = M.x * M.y;
            const float s12  = z - mu12;
            const float num = fmaf(2.f, mu12, C1) * fmaf(2.f, s12, C2);
            const float den = (M2.x + M2.y + C1) * (S.x + S.y + C2);
            acc += num * fast_rcp(den);
        }
    }

    // ---- block reduction (8 waves) ----
    #pragma unroll
    for (int off = 32; off > 0; off >>= 1)
        acc += __shfl_down(acc, off, 64);
    const int lane = tid & 63;
    const int wv_i = tid >> 6;
    if (lane == 0) wsum[wv_i] = acc;
    __syncthreads();
    if (tid == 0) {
        float s = 0.f;
        #pragma unroll
        for (int w = 0; w < 8; w++) s += wsum[w];
        partial[blk] = s;
    }
}

__global__ __launch_bounds__(256) void ssim_reduce_kernel(
    const float* __restrict__ partial, float* __restrict__ out)
{
    float acc = 0.f;
    for (int i = threadIdx.x; i < NBLOCKS; i += 256)
        acc += partial[i];
    #pragma unroll
    for (int off = 32; off > 0; off >>= 1)
        acc += __shfl_down(acc, off, 64);
    __shared__ float wsum[4];
    const int lane = threadIdx.x & 63;
    const int wv_i = threadIdx.x >> 6;
    if (lane == 0) wsum[wv_i] = acc;
    __syncthreads();
    if (threadIdx.x == 0)
        out[0] = ((wsum[0] + wsum[1]) + (wsum[2] + wsum[3])) * (1.0f / NPIX);
}

extern "C" void kernel_launch(void* const* d_in, const int* in_sizes, int n_in,
                              void* d_out, int out_size, void* d_ws, size_t ws_size,
                              hipStream_t stream) {
    const float* img1 = (const float*)d_in[0];
    const float* img2 = (const float*)d_in[1];
    float* out = (float*)d_out;
    float* partial = (float*)d_ws;   // NBLOCKS floats of scratch

    ssim_kernel<<<NBLOCKS, BLK_T, 0, stream>>>(img1, img2, partial);
    ssim_reduce_kernel<<<1, 256, 0, stream>>>(partial, out);
}